// Round 3
// baseline (333.359 us; speedup 1.0000x reference)
//
#include <hip/hip_runtime.h>

#define SEQn   512
#define BATCHn 4096
#define INn    9
#define HIDn   64
#define OUTn   10

typedef __attribute__((ext_vector_type(4))) float f32x4;

__device__ __forceinline__ float fast_tanh(float x){
    // tanh(x) = 1 - 2/(exp(2x)+1); exp via exp2, saturates correctly
    float e = __builtin_amdgcn_exp2f(x * 2.8853900817779268f);
    float r = __builtin_amdgcn_rcpf(e + 1.0f);
    return __builtin_fmaf(-2.0f, r, 1.0f);
}

// Only batch row 4095 reaches the output (feat = h2[:, -1, :] indexes BATCH axis).
// Entire computation = 512 sequential steps of 64-wide matvecs for one batch row.
// One block, 4 waves, lag-pipelined stages, one barrier per iteration:
//   W0: h1[t] = tanh(x[t]·Wih0^T + h1[t-1]·Whh0^T + b1)      (iter i = t)
//   W1: u[t]  = h1[t]·Wih1^T                                  (iter i = t+1)
//   W2: h2[t] = tanh(u[t] + h2[t-1]·Whh1^T + b2)              (iter i = t+2)
//   W3: out[t]= h2[t]·Wfc^T + bfc  -> LDS outbuf              (iter i = t+3)
// Weight rows live in VGPRs (lane n owns row n); h ping-pongs through LDS.
// No global memory ops inside the loop (x pre-staged, out post-dumped).
extern "C" __global__ __launch_bounds__(256, 1)
void rnn_lastrow(const float* __restrict__ x,
                 const float* __restrict__ Wih0, const float* __restrict__ Whh0,
                 const float* __restrict__ bih0, const float* __restrict__ bhh0,
                 const float* __restrict__ Wih1, const float* __restrict__ Whh1,
                 const float* __restrict__ bih1, const float* __restrict__ bhh1,
                 const float* __restrict__ Wfc,  const float* __restrict__ bfc,
                 float* __restrict__ out)
{
    __shared__ __align__(16) float xl[SEQn*12];        // x[:,4095,:], rows padded to 12
    __shared__ __align__(16) float h1buf[2][HIDn];
    __shared__ __align__(16) float ubuf [2][HIDn];
    __shared__ __align__(16) float h2buf[2][HIDn];
    __shared__ __align__(16) float outbuf[SEQn*OUTn];

    const int tid  = threadIdx.x;
    const int w    = tid >> 6;
    const int lane = tid & 63;

    // ---- stage x[:, 4095, :] into LDS (one-time gather) ----
    for (int idx = tid; idx < SEQn*INn; idx += 256){
        int s = idx / INn, ii = idx - s*INn;
        xl[s*12 + ii] = x[((long)s*BATCHn + (BATCHn-1))*INn + ii];
    }
    if (tid < 128){
        (&h1buf[0][0])[tid] = 0.f;   // h1[-1] = 0
        (&ubuf [0][0])[tid] = 0.f;
        (&h2buf[0][0])[tid] = 0.f;   // h2[-1] = 0
    }

    // ---- weights -> registers: lane n holds row n of this wave's matrix ----
    float wrow[64];
    float wx9[9];
    float bias = 0.f;
    {
        const float* Wm = (w==0) ? Whh0 : (w==1) ? Wih1 : (w==2) ? Whh1 : Wfc;
        if (w < 3 || lane < OUTn){
#pragma unroll
            for (int c = 0; c < 16; ++c){
                f32x4 v = *(const f32x4*)&Wm[lane*64 + c*4];
                wrow[4*c+0] = v.x; wrow[4*c+1] = v.y;
                wrow[4*c+2] = v.z; wrow[4*c+3] = v.w;
            }
        }
        if (w == 0){
#pragma unroll
            for (int c = 0; c < 9; ++c) wx9[c] = Wih0[lane*INn + c];
            bias = bih0[lane] + bhh0[lane];
        } else if (w == 2){
            bias = bih1[lane] + bhh1[lane];
        } else if (w == 3 && lane < OUTn){
            bias = bfc[lane];
        }
    }
    __syncthreads();

    // ---- 512+3 pipelined iterations, one barrier each ----
    for (int i = 0; i < SEQn + 3; ++i){
        if (w == 0){
            if (i < SEQn){
                const float* hp = h1buf[(i+1)&1];          // h1[i-1]
                const float* xr = &xl[i*12];
                f32x4 x0 = *(const f32x4*)&xr[0];
                f32x4 x1 = *(const f32x4*)&xr[4];
                float x8 = xr[8];
                float a0 = bias, a1 = 0.f, a2 = 0.f, a3 = 0.f;
                a0 = __builtin_fmaf(x0.x, wx9[0], a0); a1 = __builtin_fmaf(x0.y, wx9[1], a1);
                a2 = __builtin_fmaf(x0.z, wx9[2], a2); a3 = __builtin_fmaf(x0.w, wx9[3], a3);
                a0 = __builtin_fmaf(x1.x, wx9[4], a0); a1 = __builtin_fmaf(x1.y, wx9[5], a1);
                a2 = __builtin_fmaf(x1.z, wx9[6], a2); a3 = __builtin_fmaf(x1.w, wx9[7], a3);
                a0 = __builtin_fmaf(x8,   wx9[8], a0);
#pragma unroll
                for (int jb = 0; jb < 16; ++jb){
                    f32x4 v = *(const f32x4*)&hp[jb*4];
                    a0 = __builtin_fmaf(v.x, wrow[4*jb+0], a0);
                    a1 = __builtin_fmaf(v.y, wrow[4*jb+1], a1);
                    a2 = __builtin_fmaf(v.z, wrow[4*jb+2], a2);
                    a3 = __builtin_fmaf(v.w, wrow[4*jb+3], a3);
                }
                h1buf[i&1][lane] = fast_tanh((a0+a1)+(a2+a3));
            }
        } else if (w == 1){
            int t = i - 1;
            if (t >= 0 && t < SEQn){
                const float* hp = h1buf[t&1];              // h1[t]
                float a0 = 0.f, a1 = 0.f, a2 = 0.f, a3 = 0.f;
#pragma unroll
                for (int jb = 0; jb < 16; ++jb){
                    f32x4 v = *(const f32x4*)&hp[jb*4];
                    a0 = __builtin_fmaf(v.x, wrow[4*jb+0], a0);
                    a1 = __builtin_fmaf(v.y, wrow[4*jb+1], a1);
                    a2 = __builtin_fmaf(v.z, wrow[4*jb+2], a2);
                    a3 = __builtin_fmaf(v.w, wrow[4*jb+3], a3);
                }
                ubuf[t&1][lane] = (a0+a1)+(a2+a3);
            }
        } else if (w == 2){
            int t = i - 2;
            if (t >= 0 && t < SEQn){
                const float* hp = h2buf[(t+1)&1];          // h2[t-1]
                float a0 = bias + ubuf[t&1][lane];
                float a1 = 0.f, a2 = 0.f, a3 = 0.f;
#pragma unroll
                for (int jb = 0; jb < 16; ++jb){
                    f32x4 v = *(const f32x4*)&hp[jb*4];
                    a0 = __builtin_fmaf(v.x, wrow[4*jb+0], a0);
                    a1 = __builtin_fmaf(v.y, wrow[4*jb+1], a1);
                    a2 = __builtin_fmaf(v.z, wrow[4*jb+2], a2);
                    a3 = __builtin_fmaf(v.w, wrow[4*jb+3], a3);
                }
                h2buf[t&1][lane] = fast_tanh((a0+a1)+(a2+a3));
            }
        } else {
            int t = i - 3;
            if (t >= 0 && t < SEQn && lane < OUTn){
                const float* hp = h2buf[t&1];              // h2[t]
                float a0 = bias, a1 = 0.f, a2 = 0.f, a3 = 0.f;
#pragma unroll
                for (int jb = 0; jb < 16; ++jb){
                    f32x4 v = *(const f32x4*)&hp[jb*4];
                    a0 = __builtin_fmaf(v.x, wrow[4*jb+0], a0);
                    a1 = __builtin_fmaf(v.y, wrow[4*jb+1], a1);
                    a2 = __builtin_fmaf(v.z, wrow[4*jb+2], a2);
                    a3 = __builtin_fmaf(v.w, wrow[4*jb+3], a3);
                }
                outbuf[t*OUTn + lane] = (a0+a1)+(a2+a3);
            }
        }
        __syncthreads();
    }

    // ---- dump outbuf -> global, coalesced ----
    for (int idx = tid; idx < SEQn*OUTn; idx += 256)
        out[idx] = outbuf[idx];
}

extern "C" void kernel_launch(void* const* d_in, const int* in_sizes, int n_in,
                              void* d_out, int out_size, void* d_ws, size_t ws_size,
                              hipStream_t stream){
    rnn_lastrow<<<dim3(1), dim3(256), 0, stream>>>(
        (const float*)d_in[0],
        (const float*)d_in[1], (const float*)d_in[2],
        (const float*)d_in[3], (const float*)d_in[4],
        (const float*)d_in[5], (const float*)d_in[6],
        (const float*)d_in[7], (const float*)d_in[8],
        (const float*)d_in[9], (const float*)d_in[10],
        (float*)d_out);
}

// Round 4
// 305.324 us; speedup vs baseline: 1.0918x; 1.0918x over previous
//
#include <hip/hip_runtime.h>

#define SEQn   512
#define BATCHn 4096
#define INn    9
#define HIDn   64
#define OUTn   10

typedef __attribute__((ext_vector_type(4))) float f32x4;
typedef _Float16 half2_t __attribute__((ext_vector_type(2)));

#if __has_builtin(__builtin_amdgcn_fdot2)
#define DOT2(a, b, c) __builtin_amdgcn_fdot2((a), (b), (c), false)
#else
__device__ __forceinline__ float DOT2(half2_t a, half2_t b, float c){
    return __builtin_fmaf((float)a.x, (float)b.x,
           __builtin_fmaf((float)a.y, (float)b.y, c));
}
#endif

__device__ __forceinline__ float fast_tanh(float x){
    float e = __builtin_amdgcn_exp2f(x * 2.8853900817779268f);  // e^(2x)
    float r = __builtin_amdgcn_rcpf(e + 1.0f);
    return __builtin_fmaf(-2.0f, r, 1.0f);
}

// lane-owned weight row (64 f32 -> 32 half2 regs)
__device__ __forceinline__ void load_wrow_f16(const float* __restrict__ W, int row,
                                              half2_t* wr){
#pragma unroll
    for (int c = 0; c < 16; ++c){
        f32x4 v = *(const f32x4*)&W[row*64 + c*4];
        wr[2*c]   = half2_t{(_Float16)v.x, (_Float16)v.y};
        wr[2*c+1] = half2_t{(_Float16)v.z, (_Float16)v.w};
    }
}

// 64-wide dot: h (f16, LDS broadcast reads) . wrow (f16 regs), fp32 accumulate
__device__ __forceinline__ float dot64(const _Float16* __restrict__ hp,
                                       const half2_t* wr, float acc0){
    float a0 = acc0, a1 = 0.f, a2 = 0.f, a3 = 0.f;
#pragma unroll
    for (int jb = 0; jb < 8; ++jb){
        uint4 v = *(const uint4*)(hp + jb*8);   // ds_read_b128, wave-uniform addr
        a0 = DOT2(__builtin_bit_cast(half2_t, v.x), wr[jb*4+0], a0);
        a1 = DOT2(__builtin_bit_cast(half2_t, v.y), wr[jb*4+1], a1);
        a2 = DOT2(__builtin_bit_cast(half2_t, v.z), wr[jb*4+2], a2);
        a3 = DOT2(__builtin_bit_cast(half2_t, v.w), wr[jb*4+3], a3);
    }
    return (a0 + a1) + (a2 + a3);
}

// Only batch row 4095 reaches the output. 1 block, 4 waves, lag-pipeline, one
// barrier/iter. Critical recurrences (W0,W2) are stripped to the bare 64x64
// matvec (f16 dot2): input-side terms precomputed off-path.
//   W0 @ i:   h1[i] = tanh(u1[i] + Whh0.h1[i-1])
//   W1 @ i:   u2[i-1] = Wih1.h1[i-1] + b2
//   W2 @ i:   h2[i-2] = tanh(u2[i-2] + Whh1.h2[i-3])
//   W3 @ i:   u1[i+1] = x[i+1].Wih0^T + b1   and   out[i-3] = Wfc.h2[i-3] + bfc
extern "C" __global__ __launch_bounds__(256, 1)
void rnn_lastrow(const float* __restrict__ x,
                 const float* __restrict__ Wih0, const float* __restrict__ Whh0,
                 const float* __restrict__ bih0, const float* __restrict__ bhh0,
                 const float* __restrict__ Wih1, const float* __restrict__ Whh1,
                 const float* __restrict__ bih1, const float* __restrict__ bhh1,
                 const float* __restrict__ Wfc,  const float* __restrict__ bfc,
                 float* __restrict__ out)
{
    __shared__ __align__(16) float    xl[SEQn*12];        // x[:,4095,:], stride 12
    __shared__ __align__(16) _Float16 h1buf[2][HIDn];
    __shared__ __align__(16) _Float16 h2buf[2][HIDn];
    __shared__ __align__(16) float    u1buf[2][HIDn];
    __shared__ __align__(16) float    u2buf[2][HIDn];
    __shared__ __align__(16) float    outbuf[SEQn*OUTn];

    const int tid  = threadIdx.x;
    const int w    = tid >> 6;
    const int lane = tid & 63;

    // ---- stage x[:, 4095, :] into LDS ----
    for (int idx = tid; idx < SEQn*INn; idx += 256){
        int s = idx / INn, ii = idx - s*INn;
        xl[s*12 + ii] = x[((long)s*BATCHn + (BATCHn-1))*INn + ii];
    }
    if (tid < 64){   // h1[-1] = h2[-1] = 0 (both parities for safety)
        ((unsigned*)h1buf)[tid] = 0u;
        ((unsigned*)h2buf)[tid] = 0u;
    }

    // ---- per-wave weights -> registers ----
    half2_t wroh[32];
    float   wx9[9];
    float   bias = 0.f, biasfc = 0.f;
    if (w == 0){
        load_wrow_f16(Whh0, lane, wroh);
    } else if (w == 1){
        load_wrow_f16(Wih1, lane, wroh);
        bias = bih1[lane] + bhh1[lane];
    } else if (w == 2){
        load_wrow_f16(Whh1, lane, wroh);
    } else {
#pragma unroll
        for (int j = 0; j < INn; ++j) wx9[j] = Wih0[lane*INn + j];
        bias = bih0[lane] + bhh0[lane];
        if (lane < OUTn){
            load_wrow_f16(Wfc, lane, wroh);
            biasfc = bfc[lane];
        }
        // prestage u1[0] straight from global (off critical path)
        const float* xg = x + ((long)0*BATCHn + (BATCHn-1))*INn;
        float a0 = bias, a1 = 0.f, a2 = 0.f;
        a0 = __builtin_fmaf(xg[0], wx9[0], a0);
        a1 = __builtin_fmaf(xg[1], wx9[1], a1);
        a2 = __builtin_fmaf(xg[2], wx9[2], a2);
        a0 = __builtin_fmaf(xg[3], wx9[3], a0);
        a1 = __builtin_fmaf(xg[4], wx9[4], a1);
        a2 = __builtin_fmaf(xg[5], wx9[5], a2);
        a0 = __builtin_fmaf(xg[6], wx9[6], a0);
        a1 = __builtin_fmaf(xg[7], wx9[7], a1);
        a2 = __builtin_fmaf(xg[8], wx9[8], a2);
        u1buf[0][lane] = (a0 + a1) + a2;
    }
    __syncthreads();

    // ---- 512+3 pipelined iterations, one barrier each ----
    for (int i = 0; i < SEQn + 3; ++i){
        const int par = i & 1;
        if (w == 0){
            if (i < SEQn){
                float v = dot64(h1buf[par^1], wroh, u1buf[par][lane]);
                h1buf[par][lane] = (_Float16)fast_tanh(v);
            }
        } else if (w == 1){
            if (i >= 1 && i <= SEQn){
                float v = dot64(h1buf[par^1], wroh, bias);
                u2buf[par^1][lane] = v;
            }
        } else if (w == 2){
            if (i >= 2 && i <= SEQn + 1){
                float v = dot64(h2buf[par^1], wroh, u2buf[par][lane]);
                h2buf[par][lane] = (_Float16)fast_tanh(v);
            }
        } else {
            if (i + 1 < SEQn){
                const float* xr = &xl[(i+1)*12];
                f32x4 x0 = *(const f32x4*)&xr[0];
                f32x4 x1 = *(const f32x4*)&xr[4];
                float x8 = xr[8];
                float a0 = bias, a1 = 0.f, a2 = 0.f;
                a0 = __builtin_fmaf(x0.x, wx9[0], a0);
                a1 = __builtin_fmaf(x0.y, wx9[1], a1);
                a2 = __builtin_fmaf(x0.z, wx9[2], a2);
                a0 = __builtin_fmaf(x0.w, wx9[3], a0);
                a1 = __builtin_fmaf(x1.x, wx9[4], a1);
                a2 = __builtin_fmaf(x1.y, wx9[5], a2);
                a0 = __builtin_fmaf(x1.z, wx9[6], a0);
                a1 = __builtin_fmaf(x1.w, wx9[7], a1);
                a2 = __builtin_fmaf(x8,   wx9[8], a2);
                u1buf[par^1][lane] = (a0 + a1) + a2;
            }
            if (i >= 3 && lane < OUTn){
                float v = dot64(h2buf[par^1], wroh, biasfc);
                outbuf[(i-3)*OUTn + lane] = v;
            }
        }
        __syncthreads();
    }

    // ---- dump outbuf -> global ----
    for (int idx = tid; idx < SEQn*OUTn; idx += 256)
        out[idx] = outbuf[idx];
}

extern "C" void kernel_launch(void* const* d_in, const int* in_sizes, int n_in,
                              void* d_out, int out_size, void* d_ws, size_t ws_size,
                              hipStream_t stream){
    rnn_lastrow<<<dim3(1), dim3(256), 0, stream>>>(
        (const float*)d_in[0],
        (const float*)d_in[1], (const float*)d_in[2],
        (const float*)d_in[3], (const float*)d_in[4],
        (const float*)d_in[5], (const float*)d_in[6],
        (const float*)d_in[7], (const float*)d_in[8],
        (const float*)d_in[9], (const float*)d_in[10],
        (float*)d_out);
}